// Round 10
// baseline (247.063 us; speedup 1.0000x reference)
//
#include <hip/hip_runtime.h>
#include <math.h>

// Problem constants: B=64, D=128, N=500000, K+1=4096
constexpr int Bb   = 64;
constexpr int Dd   = 128;
constexpr int KP1  = 4096;
constexpr int Nrow = 500000;           // rows per bank
constexpr long NMEM = (long)Nrow * Dd; // elements per bank
constexpr int BK   = Bb * KP1;         // 262144 per score output
constexpr long HALF_F4 = NMEM / 4;     // 16,000,000 f4 per bank

// streaming-score machinery
constexpr int GPB  = 15625;            // 1024-f4 groups per bank (32 rows each)
constexpr int NBLK = 512;              // copy_score blocks (even: bank = blk&1)
constexpr int NWB  = (NBLK / 2) * 8;   // waves per bank = 2048
constexpr int OVSLOT = 15;             // overflow entries per row (cap 16 total)
constexpr long META_B    = (long)Nrow * 8;            // int2 meta
constexpr long ENTRIES_B = (long)Nrow * OVSLOT * 4;   // 30 MB
constexpr long WS_NEED   = META_B + ENTRIES_B;        // 34 MB

typedef float f4 __attribute__((ext_vector_type(4)));

// Output layout: [0,BK) out_image | [BK,2BK) out_gene | new banks (image,gene)
__device__ __forceinline__ float dot8(float4 a, float4 b, float4 x0, float4 x1) {
    return a.x*x0.x + a.y*x0.y + a.z*x0.z + a.w*x0.w
         + b.x*x1.x + b.y*x1.y + b.z*x1.z + b.w*x1.w;
}

// ============ streaming-score path ============

// one thread per idx entry j (j = b*4096+k)
__global__ __launch_bounds__(512) void build_inv(
    const int* __restrict__ idx, int2* __restrict__ meta, int* __restrict__ entries)
{
    const int j = blockIdx.x * 512 + threadIdx.x;   // grid 512 -> 262144 threads
    const int r = idx[j];
    const int c = atomicAdd(&meta[r].x, 1);
    if (c == 0) meta[r].y = j;
    else if (c <= OVSLOT) entries[(long)r * OVSLOT + (c - 1)] = j;
}

// Copy both banks (pure streaming, wave-autonomous) + match scores from
// L2-hot re-reads. Block bank = blockIdx.x & 1:
//   bank0: image rows, dot gene[b]  -> out_gene (out+BK)
//   bank1: gene rows,  dot image[b] -> out_image (out)
__global__ __launch_bounds__(512, 4) void copy_score(
    const float* __restrict__ image, const float* __restrict__ gene,
    const float* __restrict__ mem_image, const float* __restrict__ mem_gene,
    const int2* __restrict__ meta, const int* __restrict__ entries,
    float* __restrict__ out)
{
    const int tid  = threadIdx.x;
    const int bank = blockIdx.x & 1;
    const int wid  = tid >> 6;            // wave in block 0..7
    const int lane = tid & 63;
    const int lg   = lane & 15;           // lane in 16-lane subgroup
    const int sgid = (lane >> 4) & 3;     // subgroup 0..3

    __shared__ f4 lx[2048];               // 32 KB: x matrix for my direction
    {
        const f4* gx = bank ? (const f4*)image : (const f4*)gene;
        #pragma unroll
        for (int u = 0; u < 4; ++u) lx[u * 512 + tid] = gx[u * 512 + tid];
    }
    __syncthreads();

    const f4* src = bank ? (const f4*)mem_gene : (const f4*)mem_image;
    f4* dst = (f4*)(out + 2 * BK) + (bank ? HALF_F4 : 0);
    float* odir = bank ? out : out + BK;

    // contiguous group range for this wave
    const int wb = (blockIdx.x >> 1) * 8 + wid;        // 0..2047 within bank
    const long gs = (long)wb * GPB / NWB;
    const long ge = (long)(wb + 1) * GPB / NWB;

    for (long g = gs; g < ge; ++g) {
        const long fbase = g * 1024;
        const int  grow0 = (int)g * 32;

        // ---- copy: 16 loads in flight, then 16 nt-stores ----
        f4 v[16];
        #pragma unroll
        for (int t = 0; t < 16; ++t) v[t] = src[fbase + t * 64 + lane];
        int2 mt = make_int2(0, 0);
        if (lane < 32) mt = meta[grow0 + lane];
        #pragma unroll
        for (int t = 0; t < 16; ++t)
            __builtin_nontemporal_store(v[t], dst + fbase + t * 64 + lane);

        // ---- match: 4 subgroups x 8 rows, src rows are L2-hot ----
        for (int i = 0; i < 8; ++i) {
            const int rr = sgid + 4 * i;
            // BOTH shuffles while all 64 lanes are active (loop header
            // reconvergence). Shuffling after the divergent `continue`
            // sources inactive lanes -> undefined data (the R9 bug).
            const int n0 = __shfl(mt.x, rr);
            const int j0 = __shfl(mt.y, rr);
            if (n0 <= 0) continue;
            const int n = (n0 <= OVSLOT + 1) ? n0 : OVSLOT + 1;
            int j = j0;
            const long rbase = (long)(grow0 + rr) * 32;
            const f4 r0 = src[rbase + lg];
            const f4 r1 = src[rbase + 16 + lg];
            for (int e = 0;;) {
                const int bq = j >> 12;
                const f4 x0 = lx[bq * 32 + lg];
                const f4 x1 = lx[bq * 32 + 16 + lg];
                float s = r0.x*x0.x + r0.y*x0.y + r0.z*x0.z + r0.w*x0.w
                        + r1.x*x1.x + r1.y*x1.y + r1.z*x1.z + r1.w*x1.w;
                s += __shfl_xor(s, 1);
                s += __shfl_xor(s, 2);
                s += __shfl_xor(s, 4);
                s += __shfl_xor(s, 8);
                if (lg == 0) odir[j] = s;
                if (++e >= n) break;
                j = entries[(long)(grow0 + rr) * OVSLOT + (e - 1)];
            }
        }
    }
}

// Epilogue: blocks [0,128) in-place row softmax; blocks [128,160) momentum update.
__global__ __launch_bounds__(512) void epilogue(
    const float* __restrict__ image, const float* __restrict__ gene,
    const float* __restrict__ mem_image, const float* __restrict__ mem_gene,
    const int* __restrict__ index, float* __restrict__ out)
{
    const int tid = threadIdx.x;

    if (blockIdx.x < 128) {
        f4* row = (f4*)(out + (long)blockIdx.x * KP1);
        __shared__ float red[8];

        f4 a = row[tid], b = row[tid + 512];
        float m = fmaxf(fmaxf(fmaxf(a.x, a.y), fmaxf(a.z, a.w)),
                        fmaxf(fmaxf(b.x, b.y), fmaxf(b.z, b.w)));
        #pragma unroll
        for (int off = 1; off < 64; off <<= 1) m = fmaxf(m, __shfl_xor(m, off));
        if ((tid & 63) == 0) red[tid >> 6] = m;
        __syncthreads();
        if (tid < 64) {
            float tv = (tid < 8) ? red[tid] : -INFINITY;
            #pragma unroll
            for (int off = 1; off < 8; off <<= 1) tv = fmaxf(tv, __shfl_xor(tv, off));
            if (tid == 0) red[0] = tv;
        }
        __syncthreads();
        m = red[0];
        __syncthreads();

        a.x = expf(a.x - m); a.y = expf(a.y - m); a.z = expf(a.z - m); a.w = expf(a.w - m);
        b.x = expf(b.x - m); b.y = expf(b.y - m); b.z = expf(b.z - m); b.w = expf(b.w - m);
        float sum = a.x + a.y + a.z + a.w + b.x + b.y + b.z + b.w;
        #pragma unroll
        for (int off = 1; off < 64; off <<= 1) sum += __shfl_xor(sum, off);
        if ((tid & 63) == 0) red[tid >> 6] = sum;
        __syncthreads();
        if (tid < 64) {
            float tv = (tid < 8) ? red[tid] : 0.f;
            #pragma unroll
            for (int off = 1; off < 8; off <<= 1) tv += __shfl_xor(tv, off);
            if (tid == 0) red[0] = tv;
        }
        __syncthreads();
        const float inv = 1.0f / red[0];
        a *= inv; b *= inv;
        row[tid] = a; row[tid + 512] = b;
        return;
    }

    // momentum: 32 blocks x 4 tasks (task = 128 threads)
    const int task  = ((blockIdx.x - 128) << 2) | (tid >> 7);  // 0..127
    const int sub   = tid >> 7;
    const int d     = tid & 127;
    const int which = task >> 6;       // 0 -> image bank, 1 -> gene bank
    const int b     = task & 63;
    const float* mem = which ? mem_gene : mem_image;
    const float* x   = which ? gene : image;
    float* o = out + 2 * BK + (long)which * NMEM;

    const long row = index[b];
    float p = mem[row * Dd + d] * 0.5f + x[(long)b * Dd + d] * 0.5f;
    float ss = p * p;
    #pragma unroll
    for (int off = 1; off < 64; off <<= 1) ss += __shfl_xor(ss, off);
    __shared__ float r2[8];
    if ((tid & 63) == 0) r2[tid >> 6] = ss;
    __syncthreads();
    const float inv = 1.0f / sqrtf(r2[2 * sub] + r2[2 * sub + 1]);
    o[row * Dd + d] = p * inv;
}

// ============ fallback (proven R6) pieces ============

constexpr int  CHUNK_F4   = 8192;
constexpr int  FULL_PER_B = 1953;
constexpr long TAIL_BASE  = (long)FULL_PER_B * CHUNK_F4;
constexpr int  CHUNKS_PER_BANK = FULL_PER_B + 1;
constexpr int  NCHUNK     = 2 * CHUNKS_PER_BANK;

__global__ __launch_bounds__(64) void zero_ctr(unsigned* ctr) {
    if (threadIdx.x == 0) *ctr = 0u;
}

__global__ __launch_bounds__(512, 2) void fused_scores_copy(
    const float* __restrict__ image, const float* __restrict__ gene,
    const float* __restrict__ mem_image, const float* __restrict__ mem_gene,
    const int* __restrict__ idx, float* __restrict__ out, unsigned* __restrict__ ctr)
{
    const int tid = threadIdx.x;

    if (blockIdx.x < 128) {
        const int b     = blockIdx.x >> 1;
        const int which = blockIdx.x & 1;
        const float* w = which ? mem_image : mem_gene;
        const float* x = which ? gene : image;
        float* o = out + (long)which * BK + (long)b * KP1;

        __shared__ int   sidx[KP1];
        __shared__ float sv[KP1];
        __shared__ float red[8];
        {
            const int4* s4 = (const int4*)(idx + (long)b * KP1);
            int4* d4 = (int4*)sidx;
            d4[tid]       = s4[tid];
            d4[tid + 512] = s4[tid + 512];
        }
        const int lg  = tid & 15;
        const int grp = tid >> 4;
        float4 x0 = *(const float4*)(x + b * Dd + lg * 8);
        float4 x1 = *(const float4*)(x + b * Dd + lg * 8 + 4);
        __syncthreads();

        for (int j = 0; j < 128; j += 4) {
            const int k0 = grp + (j + 0) * 32;
            const int k1 = grp + (j + 1) * 32;
            const int k2 = grp + (j + 2) * 32;
            const int k3 = grp + (j + 3) * 32;
            const float4* r0 = (const float4*)(w + (long)sidx[k0] * Dd + lg * 8);
            const float4* r1 = (const float4*)(w + (long)sidx[k1] * Dd + lg * 8);
            const float4* r2 = (const float4*)(w + (long)sidx[k2] * Dd + lg * 8);
            const float4* r3 = (const float4*)(w + (long)sidx[k3] * Dd + lg * 8);
            float4 a0 = r0[0], b0 = r0[1];
            float4 a1 = r1[0], b1 = r1[1];
            float4 a2 = r2[0], b2 = r2[1];
            float4 a3 = r3[0], b3 = r3[1];
            float d0 = dot8(a0, b0, x0, x1);
            float d1 = dot8(a1, b1, x0, x1);
            float d2 = dot8(a2, b2, x0, x1);
            float d3 = dot8(a3, b3, x0, x1);
            d0 += __shfl_xor(d0, 1); d1 += __shfl_xor(d1, 1);
            d2 += __shfl_xor(d2, 1); d3 += __shfl_xor(d3, 1);
            d0 += __shfl_xor(d0, 2); d1 += __shfl_xor(d1, 2);
            d2 += __shfl_xor(d2, 2); d3 += __shfl_xor(d3, 2);
            d0 += __shfl_xor(d0, 4); d1 += __shfl_xor(d1, 4);
            d2 += __shfl_xor(d2, 4); d3 += __shfl_xor(d3, 4);
            d0 += __shfl_xor(d0, 8); d1 += __shfl_xor(d1, 8);
            d2 += __shfl_xor(d2, 8); d3 += __shfl_xor(d3, 8);
            if (lg == 0) { sv[k0] = d0; sv[k1] = d1; sv[k2] = d2; sv[k3] = d3; }
        }
        __syncthreads();

        float m = fmaxf(sv[tid], sv[tid + 512]);
        m = fmaxf(m, fmaxf(sv[tid + 1024], sv[tid + 1536]));
        m = fmaxf(m, fmaxf(sv[tid + 2048], sv[tid + 2560]));
        m = fmaxf(m, fmaxf(sv[tid + 3072], sv[tid + 3584]));
        #pragma unroll
        for (int off = 1; off < 64; off <<= 1) m = fmaxf(m, __shfl_xor(m, off));
        if ((tid & 63) == 0) red[tid >> 6] = m;
        __syncthreads();
        if (tid < 64) {
            float tv = (tid < 8) ? red[tid] : -INFINITY;
            #pragma unroll
            for (int off = 1; off < 8; off <<= 1) tv = fmaxf(tv, __shfl_xor(tv, off));
            if (tid == 0) red[0] = tv;
        }
        __syncthreads();
        m = red[0];
        __syncthreads();

        float sum = 0.f;
        #pragma unroll
        for (int r = 0; r < 8; ++r) {
            int k = tid + r * 512;
            float e = expf(sv[k] - m);
            sv[k] = e;
            sum += e;
        }
        #pragma unroll
        for (int off = 1; off < 64; off <<= 1) sum += __shfl_xor(sum, off);
        if ((tid & 63) == 0) red[tid >> 6] = sum;
        __syncthreads();
        if (tid < 64) {
            float tv = (tid < 8) ? red[tid] : 0.f;
            #pragma unroll
            for (int off = 1; off < 8; off <<= 1) tv += __shfl_xor(tv, off);
            if (tid == 0) red[0] = tv;
        }
        __syncthreads();
        const float inv = 1.0f / red[0];
        #pragma unroll
        for (int r = 0; r < 8; ++r) { int k = tid + r * 512; o[k] = sv[k] * inv; }
    }

    const f4* srcI = (const f4*)mem_image;
    const f4* srcG = (const f4*)mem_gene;
    f4* dst = (f4*)(out + 2 * BK);

    __shared__ unsigned sc;
    for (;;) {
        if (tid == 0) sc = atomicAdd(ctr, 1u);
        __syncthreads();
        const unsigned c = sc;
        __syncthreads();
        if (c >= NCHUNK) break;
        const int  bank  = (c < CHUNKS_PER_BANK) ? 0 : 1;
        const int  local = bank ? (int)(c - CHUNKS_PER_BANK) : (int)c;
        const f4*  sbank = bank ? srcG : srcI;
        const long dbank = (long)bank * HALF_F4;
        if (local < FULL_PER_B) {
            const long base = (long)local * CHUNK_F4;
            f4 v[16];
            #pragma unroll
            for (int k = 0; k < 16; ++k) v[k] = sbank[base + k * 512 + tid];
            #pragma unroll
            for (int k = 0; k < 16; ++k)
                __builtin_nontemporal_store(v[k], dst + dbank + base + k * 512 + tid);
        } else {
            f4 v0 = sbank[TAIL_BASE + tid];
            f4 v1 = sbank[TAIL_BASE + 512 + tid];
            __builtin_nontemporal_store(v0, dst + dbank + TAIL_BASE + tid);
            __builtin_nontemporal_store(v1, dst + dbank + TAIL_BASE + 512 + tid);
        }
    }
}

__global__ __launch_bounds__(128) void momentum_update(
    const float* __restrict__ image, const float* __restrict__ gene,
    const float* __restrict__ mem_image, const float* __restrict__ mem_gene,
    const int* __restrict__ index, float* __restrict__ out)
{
    const int b     = blockIdx.x;
    const int which = blockIdx.y;
    const float* mem = which ? mem_gene : mem_image;
    const float* x   = which ? gene : image;
    float* o = out + 2 * BK + (long)which * NMEM;
    const long row = index[b];
    const int d = threadIdx.x;
    float p = mem[row * Dd + d] * 0.5f + x[(long)b * Dd + d] * 0.5f;
    float ss = p * p;
    #pragma unroll
    for (int off = 1; off < 64; off <<= 1) ss += __shfl_xor(ss, off);
    __shared__ float r2[2];
    if ((d & 63) == 0) r2[d >> 6] = ss;
    __syncthreads();
    const float inv = 1.0f / sqrtf(r2[0] + r2[1]);
    o[row * Dd + d] = p * inv;
}

extern "C" void kernel_launch(void* const* d_in, const int* in_sizes, int n_in,
                              void* d_out, int out_size, void* d_ws, size_t ws_size,
                              hipStream_t stream) {
    const float* image     = (const float*)d_in[0];
    const float* gene      = (const float*)d_in[1];
    const float* mem_image = (const float*)d_in[2];
    const float* mem_gene  = (const float*)d_in[3];
    const int*   index     = (const int*)d_in[4];
    const int*   idx       = (const int*)d_in[5];
    float* out = (float*)d_out;

    if ((long)ws_size >= WS_NEED) {
        int2* meta   = (int2*)d_ws;
        int* entries = (int*)((char*)d_ws + META_B);
        hipMemsetAsync(meta, 0, META_B, stream);
        build_inv<<<dim3(512), 512, 0, stream>>>(idx, meta, entries);
        copy_score<<<dim3(NBLK), 512, 0, stream>>>(
            image, gene, mem_image, mem_gene, meta, entries, out);
        epilogue<<<dim3(160), 512, 0, stream>>>(
            image, gene, mem_image, mem_gene, index, out);
    } else {
        unsigned* ctr = (unsigned*)d_ws;
        zero_ctr<<<dim3(1), 64, 0, stream>>>(ctr);
        fused_scores_copy<<<dim3(2048), 512, 0, stream>>>(
            image, gene, mem_image, mem_gene, idx, out, ctr);
        momentum_update<<<dim3(64, 2), 128, 0, stream>>>(
            image, gene, mem_image, mem_gene, index, out);
    }
}